// Round 1
// baseline (615.162 us; speedup 1.0000x reference)
//
#include <hip/hip_runtime.h>

// out[b,t,h] = sum_{m<7} images[b,t,m] * A[m,h]
// images: (64,576,7) fp32   A: (4096,4096) fp32 (only first 7 rows used)
// out:    (64,576,4096) fp32  -- 604 MB pure write stream.
//
// Persistent-stream design: 2048 blocks (8/CU, co-resident), each block owns
// one 1024-col window of A in registers for its whole life and grid-strides
// over row-groups, so the store pipe never stalls on block turnover or A
// reloads. Stores use the normal cached path (the harness fill proves that
// path sustains 6.3 TB/s; nt was unproven and protects nothing here).

typedef float f4 __attribute__((ext_vector_type(4)));

#define NROWS   (64 * 576)      // 36864 (b,t) rows
#define HID     4096
#define MM      7
#define RPB     8               // rows per group: amortizes x-load latency
#define NW      4               // column windows: 4 x (256 thr * f4) = 4096
#define BLOCKS  2048            // 8 blocks/CU * 256 CUs, all co-resident
#define NGROUPS (NROWS / RPB)   // 4608
#define GSTRIDE (BLOCKS / NW)   // 512 -> 9 groups per block, exact

__global__ __launch_bounds__(256, 8) void vt_kernel(const float* __restrict__ images,
                                                    const float* __restrict__ A,
                                                    float* __restrict__ out) {
    const int w     = blockIdx.x & (NW - 1);
    const int slot  = blockIdx.x >> 2;
    const int hbase = (w << 10) + (threadIdx.x << 2);

    // A column-window fragment: loaded ONCE per block (28 VGPRs), L2-resident src.
    f4 a[MM];
#pragma unroll
    for (int m = 0; m < MM; ++m) {
        a[m] = *(const f4*)(A + (size_t)m * HID + hbase);
    }

    // Steady-state stream: per group, one uniform 56-float s_load burst
    // (224 B, wave-uniform address -> SGPRs), then 8 x (7 fma_f4 + 1 KB store).
    for (int rg = slot; rg < NGROUPS; rg += GSTRIDE) {
        const int row0 = rg * RPB;

        float x[RPB][MM];
#pragma unroll
        for (int r = 0; r < RPB; ++r) {
#pragma unroll
            for (int m = 0; m < MM; ++m) {
                x[r][m] = images[(size_t)(row0 + r) * MM + m];
            }
        }

#pragma unroll
        for (int r = 0; r < RPB; ++r) {
            f4 acc = x[r][0] * a[0];
#pragma unroll
            for (int m = 1; m < MM; ++m) {
                acc += x[r][m] * a[m];
            }
            *(f4*)(out + (size_t)(row0 + r) * HID + hbase) = acc;
        }
    }
}

extern "C" void kernel_launch(void* const* d_in, const int* in_sizes, int n_in,
                              void* d_out, int out_size, void* d_ws, size_t ws_size,
                              hipStream_t stream) {
    const float* images = (const float*)d_in[0];
    const float* A      = (const float*)d_in[1];
    float* out          = (float*)d_out;

    vt_kernel<<<BLOCKS, 256, 0, stream>>>(images, A, out);
}